// Round 9
// baseline (173.409 us; speedup 1.0000x reference)
//
#include <hip/hip_runtime.h>
#include <hip/hip_bf16.h>

typedef short bf16x8 __attribute__((ext_vector_type(8)));
typedef float f32x4  __attribute__((ext_vector_type(4)));
typedef unsigned int uint4v __attribute__((ext_vector_type(4)));

#define HWHW   3136
#define ROWSH  40            // shorts per jj slot (80 B row; 16-B units, XOR-swizzled)
#define ROWBYTES 80

__device__ __forceinline__ unsigned short f2bf(float f) {
    unsigned int u = __float_as_uint(f);
    u += 0x7fffu + ((u >> 16) & 1u);   // RNE
    return (unsigned short)(u >> 16);
}

// prepass A: W[o][c*9+t] fp32 -> lane-ordered bf16 fragments
// wt[(((t*8 + c8)*16 + om)*64 + lane)*8 + e] = W[om*16 + (lane&15)][c8*32 + (lane>>4)*8 + e]
__global__ void wprep(const float* __restrict__ w, unsigned short* __restrict__ wt) {
    int idx = blockIdx.x * blockDim.x + threadIdx.x;   // 0 .. 589823
    int e    = idx & 7;
    int lane = (idx >> 3) & 63;
    int om   = (idx >> 9) & 15;
    int c8   = (idx >> 13) & 7;
    int t    = idx >> 16;
    int o = om * 16 + (lane & 15);
    int c = c8 * 32 + (lane >> 4) * 8 + e;
    wt[idx] = f2bf(w[o * 2304 + c * 9 + t]);
}

// prepass B: x[n][c][56][56] f32 -> xt[n][c8][hp 58][wp 64][cc 32] bf16 (padded, channel-chunk-last)
__global__ void xprep(const float* __restrict__ x, unsigned short* __restrict__ xt) {
    const int hp = blockIdx.x;   // 0..57
    const int c8 = blockIdx.y;   // 0..7
    const int n  = blockIdx.z;   // 0..31
    const int t  = threadIdx.x;  // 256
    const int wp  = t >> 2;      // 0..63
    const int ccq = t & 3;       // 8 channels each
    const int h = hp - 1, w = wp - 1;
    const bool ok = (h >= 0) && (h < 56) && (w >= 0) && (w < 56);
    const int sp = ok ? (h * 56 + w) : 0;   // clamped, never OOB
    const float* xr = x + ((size_t)n * 256 + c8 * 32 + ccq * 8) * HWHW + sp;
    uint4v d;
#pragma unroll
    for (int p = 0; p < 4; ++p) {
        float f0 = ok ? xr[(size_t)(2 * p) * HWHW] : 0.0f;
        float f1 = ok ? xr[(size_t)(2 * p + 1) * HWHW] : 0.0f;
        d[p] = (unsigned)f2bf(f0) | ((unsigned)f2bf(f1) << 16);
    }
    *(uint4v*)(xt + ((((size_t)n * 8 + c8) * 58 + hp) * 2048) + wp * 32 + ccq * 8) = d;
}

__global__ __launch_bounds__(256, 2)
void conv_main(const unsigned short* __restrict__ xt, const unsigned short* __restrict__ wt,
               const float* __restrict__ bias, float* __restrict__ out) {
    __shared__ __align__(16) short xs[2][6 * 64 * ROWSH];   // 2 x 30720 B

    const int bx = blockIdx.x;   // hb*2 + bm
    const int hb = bx >> 1;      // 0..13
    const int bm = bx & 1;       // out-ch half
    const int n  = blockIdx.y;
    const int h0 = hb * 4;       // padded rows h0..h0+5 feed output rows h0..h0+3

    const int tid  = threadIdx.x;
    const int lane = tid & 63;
    const int wv   = tid >> 6;   // 0..3
    const int wm   = wv & 1;     // 64-ch group
    const int ng   = wv >> 1;    // 112-col group
    const int g    = lane >> 4;
    const int lcol = lane & 15;

    // B-frag byte offsets per (f, kw); kh handled by compile-time +kh*5120
    int bboff[7][3];
#pragma unroll
    for (int f = 0; f < 7; ++f) {
        int j = ng * 112 + f * 16 + lcol;   // 0..223
        int r = j / 56, wc = j % 56;
#pragma unroll
        for (int kw = 0; kw < 3; ++kw) {
            int ww  = wc + kw;              // 0..57
            int bit = (ww >> 3) & 1;
            bboff[f][kw] = (r * 64 + ww) * ROWBYTES + 16 * (g ^ bit);
        }
    }

    // staging map: 256 threads = 64 wp x 4 sg, each covers rows r=0..5
    const int sg  = tid & 3;
    const int swp = (tid >> 2) & 63;
    const int swb = swp * ROWBYTES + 16 * (sg ^ ((swp >> 3) & 1));   // + r*64*80

    const unsigned short* wl = wt + (size_t)lane * 8;
    const int obase = bm * 8 + wm * 4;

    f32x4 acc[4][7];
#pragma unroll
    for (int m = 0; m < 4; ++m)
#pragma unroll
        for (int f = 0; f < 7; ++f) acc[m][f] = (f32x4){0.f, 0.f, 0.f, 0.f};

    bf16x8 sv[6];
    auto s_load = [&](int c8) {
        const unsigned short* p = xt + (((size_t)n * 8 + c8) * 58 + h0) * 2048 + swp * 32 + sg * 8;
#pragma unroll
        for (int r = 0; r < 6; ++r) sv[r] = *(const bf16x8*)(p + (size_t)r * 2048);
    };
    auto s_write = [&](int buf) {
        char* d = (char*)&xs[buf][0] + swb;
#pragma unroll
        for (int r = 0; r < 6; ++r)
            *(bf16x8*)(d + r * 64 * ROWBYTES) = sv[r];
    };
    auto a_load = [&](bf16x8* dst, int c8, int t) {
#pragma unroll
        for (int m = 0; m < 4; ++m)
            dst[m] = *(const bf16x8*)(wl + (size_t)((t * 8 + c8) * 16 + obase + m) * 512);
    };

    // 3-deep A rotating prefetch: tap t uses a[t%3], tap t loads A(t+2) into
    // a[(t+2)%3]. 9 taps/chunk and 9 % 3 == 0 -> no parity flip across chunks
    // (chunk c8+1 tap 0 reads a[0], loaded at chunk c8 tap 7). 2-tap cover
    // (~500 cyc) hides L2 latency on the A stream.
    bf16x8 a[3][4];
    a_load(a[0], 0, 0);
    a_load(a[1], 0, 1);
    s_load(0);
    s_write(0);
    __syncthreads();

    for (int c8 = 0; c8 < 8; ++c8) {
        const bool more = c8 < 7;
        const char* xb = (const char*)&xs[c8 & 1][0];

#pragma unroll
        for (int t = 0; t < 9; ++t) {
            const int cur = t % 3;            // compile-time under unroll
            const int nxt = (t + 2) % 3;
            if (t < 7)      a_load(a[nxt], c8, t + 2);
            else if (more)  a_load(a[nxt], c8 + 1, t - 7);   // next chunk taps 0,1

            // write next tile just before the last MFMA cluster: the 28 MFMAs
            // cover the ds_write drain so the barrier waits on ~nothing
            if (t == 8 && more) s_write((c8 + 1) & 1);

            const int kh = t / 3, kw = t % 3;
            const int dt = kh * 64 * ROWBYTES;   // compile-time under unroll
            __builtin_amdgcn_s_setprio(1);
#pragma unroll
            for (int f = 0; f < 7; ++f) {
                bf16x8 b = *(const bf16x8*)(xb + bboff[f][kw] + dt);
#pragma unroll
                for (int m = 0; m < 4; ++m)
                    acc[m][f] = __builtin_amdgcn_mfma_f32_16x16x32_bf16(a[cur][m], b, acc[m][f], 0, 0, 0);
            }
            __builtin_amdgcn_s_setprio(0);
            // next chunk's x loads: issued ~4.5 taps (>2000 cyc) before the
            // barrier -> retired by then; sv live only taps 4..8 (no spill)
            if (t == 4 && more) s_load(c8 + 1);
        }
        __syncthreads();
    }

    // epilogue: D col = lane&15 (spatial), row = 4g+q (out-ch within 16)
#pragma unroll
    for (int m = 0; m < 4; ++m) {
#pragma unroll
        for (int q = 0; q < 4; ++q) {
            int o = bm * 128 + wm * 64 + m * 16 + 4 * g + q;
            float bs = bias[o];
            float* yo = out + ((size_t)n * 256 + o) * HWHW + hb * 224;
#pragma unroll
            for (int f = 0; f < 7; ++f) {
                int j = ng * 112 + f * 16 + lcol;
                yo[j] = acc[m][f][q] + bs;
            }
        }
    }
}

// ---------------- fallback (round-2 kernel) if ws is too small ----------------
__global__ __launch_bounds__(512, 2)
void conv_fallback(const float* __restrict__ x, const unsigned short* __restrict__ wt,
                   const float* __restrict__ bias, float* __restrict__ out) {
    __shared__ short xs[2][348 * 40];
    const int hb = blockIdx.x, n = blockIdx.y, h0 = hb * 4;
    const int tid = threadIdx.x, lane = tid & 63, wv = tid >> 6;
    const int wm = wv & 3, ng = wv >> 2, g = lane >> 4, lcol = lane & 15;
    int bbase[7];
#pragma unroll
    for (int f = 0; f < 7; ++f) {
        int j = ng * 112 + f * 16 + lcol;
        bbase[f] = ((j / 56) * 58 + (j % 56)) * 40 + 8 * g;
    }
    const int cpair = tid >> 5, col0 = tid & 31;
    const float* xn = x + (size_t)n * 256 * HWHW;
    float sv0[6][2], sv1[6][2];
    f32x4 acc[4][7];
#pragma unroll
    for (int m = 0; m < 4; ++m)
#pragma unroll
        for (int f = 0; f < 7; ++f) acc[m][f] = (f32x4){0.f, 0.f, 0.f, 0.f};
    const unsigned short* wl = wt + (size_t)lane * 8;
    auto stage_load = [&](int c8) {
        const float* xc0 = xn + (size_t)(c8 * 32 + 2 * cpair) * HWHW;
        const float* xc1 = xc0 + HWHW;
#pragma unroll
        for (int r = 0; r < 6; ++r) {
            int hh = h0 - 1 + r;
            bool rok = (hh >= 0) & (hh < 56);
#pragma unroll
            for (int ci = 0; ci < 2; ++ci) {
                int col = col0 + 32 * ci, ww = col - 1;
                bool ok = rok & (col < 58) & (ww >= 0) & (ww < 56);
                int off = hh * 56 + ww;
                sv0[r][ci] = ok ? xc0[off] : 0.0f;
                sv1[r][ci] = ok ? xc1[off] : 0.0f;
            }
        }
    };
    auto stage_write = [&](int buf) {
#pragma unroll
        for (int r = 0; r < 6; ++r)
#pragma unroll
            for (int ci = 0; ci < 2; ++ci) {
                int col = col0 + 32 * ci;
                if (col < 58) {
                    unsigned int p = (unsigned int)f2bf(sv0[r][ci]) |
                                     ((unsigned int)f2bf(sv1[r][ci]) << 16);
                    *(unsigned int*)&xs[buf][(r * 58 + col) * 40 + 2 * cpair] = p;
                }
            }
    };
    stage_load(0); stage_write(0);
    __syncthreads();
    for (int c8 = 0; c8 < 8; ++c8) {
        if (c8 < 7) stage_load(c8 + 1);
        const short* xb = &xs[c8 & 1][0];
        bf16x8 a0[4], a1[4];
#pragma unroll
        for (int m = 0; m < 4; ++m)
            a0[m] = *(const bf16x8*)(wl + (size_t)((c8 * 16) + 4 * wm + m) * 512);
#pragma unroll
        for (int t = 0; t < 9; ++t) {
            bf16x8* ac = (t & 1) ? a1 : a0;
            bf16x8* an = (t & 1) ? a0 : a1;
            if (t < 8) {
#pragma unroll
                for (int m = 0; m < 4; ++m)
                    an[m] = *(const bf16x8*)(wl + (size_t)((((t + 1) * 8 + c8) * 16) + 4 * wm + m) * 512);
            }
            const int dt = ((t / 3) * 58 + (t % 3)) * 40;
#pragma unroll
            for (int f = 0; f < 7; ++f) {
                bf16x8 b = *(const bf16x8*)&xb[bbase[f] + dt];
#pragma unroll
                for (int m = 0; m < 4; ++m)
                    acc[m][f] = __builtin_amdgcn_mfma_f32_16x16x32_bf16(ac[m], b, acc[m][f], 0, 0, 0);
            }
        }
        if (c8 < 7) stage_write((c8 + 1) & 1);
        __syncthreads();
    }
#pragma unroll
    for (int m = 0; m < 4; ++m) {
#pragma unroll
        for (int q = 0; q < 4; ++q) {
            int o = 64 * wm + 16 * m + 4 * g + q;
            float bs = bias[o];
            float* yo = out + ((size_t)n * 256 + o) * HWHW + h0 * 56;
#pragma unroll
            for (int f = 0; f < 7; ++f) {
                int j = ng * 112 + f * 16 + lcol;
                yo[j] = acc[m][f][q] + bs;
            }
        }
    }
}

extern "C" void kernel_launch(void* const* d_in, const int* in_sizes, int n_in,
                              void* d_out, int out_size, void* d_ws, size_t ws_size,
                              hipStream_t stream) {
    const float* x    = (const float*)d_in[0];
    const float* w    = (const float*)d_in[1];
    const float* bias = (const float*)d_in[2];
    float* out        = (float*)d_out;
    unsigned short* wt = (unsigned short*)d_ws;                       // 1,179,648 B
    unsigned short* xtp = (unsigned short*)((char*)d_ws + 1179648);   // 60,817,408 B

    wprep<<<2304, 256, 0, stream>>>(w, wt);
    if (ws_size >= (size_t)1179648 + 60817408) {
        xprep<<<dim3(58, 8, 32), 256, 0, stream>>>(x, xtp);
        conv_main<<<dim3(28, 32), 256, 0, stream>>>(xtp, wt, bias, out);
    } else {
        conv_fallback<<<dim3(14, 32), 512, 0, stream>>>(x, wt, bias, out);
    }
}

// Round 10
// 134.240 us; speedup vs baseline: 1.2918x; 1.2918x over previous
//
#include <hip/hip_runtime.h>
#include <hip/hip_bf16.h>

typedef short bf16x8 __attribute__((ext_vector_type(8)));
typedef float f32x4  __attribute__((ext_vector_type(4)));
typedef unsigned int uint4v __attribute__((ext_vector_type(4)));

#define HWHW   3136

__device__ __forceinline__ unsigned short f2bf(float f) {
    unsigned int u = __float_as_uint(f);
    u += 0x7fffu + ((u >> 16) & 1u);   // RNE
    return (unsigned short)(u >> 16);
}

// prepass A: W[o][c*9+t] fp32 -> lane-ordered bf16 fragments
// wt[(((t*8 + c8)*16 + om)*64 + lane)*8 + e] = W[om*16 + (lane&15)][c8*32 + (lane>>4)*8 + e]
__global__ void wprep(const float* __restrict__ w, unsigned short* __restrict__ wt) {
    int idx = blockIdx.x * blockDim.x + threadIdx.x;   // 0 .. 589823
    int e    = idx & 7;
    int lane = (idx >> 3) & 63;
    int om   = (idx >> 9) & 15;
    int c8   = (idx >> 13) & 7;
    int t    = idx >> 16;
    int o = om * 16 + (lane & 15);
    int c = c8 * 32 + (lane >> 4) * 8 + e;
    wt[idx] = f2bf(w[o * 2304 + c * 9 + t]);
}

// prepass B: x[n][c][56][56] f32 -> xt[n][c8][hp 58][wp 64][cc 32] bf16 (padded, channel-chunk-last)
__global__ void xprep(const float* __restrict__ x, unsigned short* __restrict__ xt) {
    const int hp = blockIdx.x;   // 0..57
    const int c8 = blockIdx.y;   // 0..7
    const int n  = blockIdx.z;   // 0..31
    const int t  = threadIdx.x;  // 256
    const int wp  = t >> 2;      // 0..63
    const int ccq = t & 3;       // 8 channels each
    const int h = hp - 1, w = wp - 1;
    const bool ok = (h >= 0) && (h < 56) && (w >= 0) && (w < 56);
    const int sp = ok ? (h * 56 + w) : 0;   // clamped, never OOB
    const float* xr = x + ((size_t)n * 256 + c8 * 32 + ccq * 8) * HWHW + sp;
    uint4v d;
#pragma unroll
    for (int p = 0; p < 4; ++p) {
        float f0 = ok ? xr[(size_t)(2 * p) * HWHW] : 0.0f;
        float f1 = ok ? xr[(size_t)(2 * p + 1) * HWHW] : 0.0f;
        d[p] = (unsigned)f2bf(f0) | ((unsigned)f2bf(f1) << 16);
    }
    *(uint4v*)(xt + ((((size_t)n * 8 + c8) * 58 + hp) * 2048) + wp * 32 + ccq * 8) = d;
}

__global__ __launch_bounds__(256, 2)
void conv_main(const unsigned short* __restrict__ xt, const unsigned short* __restrict__ wt,
               const float* __restrict__ bias, float* __restrict__ out) {
    // linear tile: [6 rows][64 ww][64 B = 4 units x 16 B], unit u holds k-group
    // g = u ^ (ww & 3). DMA-written linearly; XOR applied on the SOURCE address.
    __shared__ __align__(16) short xs[2][6 * 64 * 32];   // 2 x 24576 B

    // XCD swizzle: 28 consecutive co-XCD blocks share one n (x-slice 1.9MB + wt
    // 1.15MB fit the 4MB XCD L2). 896 % 8 == 0 -> bijective.
    const int bid  = blockIdx.x;
    const int bid2 = (bid & 7) * 112 + (bid >> 3);
    const int n  = bid2 / 28;
    const int r2 = bid2 % 28;
    const int hb = r2 >> 1;      // 0..13
    const int bm = r2 & 1;       // out-ch half
    const int h0 = hb * 4;       // padded rows h0..h0+5 feed output rows h0..h0+3

    const int tid  = threadIdx.x;
    const int lane = tid & 63;
    const int wv   = tid >> 6;   // 0..3
    const int wm   = wv & 1;     // 64-ch group
    const int ng   = wv >> 1;    // 112-col group
    const int g    = lane >> 4;
    const int lcol = lane & 15;

    // B-frag byte offsets per (f, kw); kh adds compile-time +kh*4096
    int bboff[7][3];
#pragma unroll
    for (int f = 0; f < 7; ++f) {
        int j = ng * 112 + f * 16 + lcol;   // 0..223
        int r = j / 56, wc = j % 56;
#pragma unroll
        for (int kw = 0; kw < 3; ++kw) {
            int ww = wc + kw;               // 0..57
            bboff[f][kw] = ((r * 64 + ww) << 6) + 16 * (g ^ (ww & 3));
        }
    }

    const unsigned short* wl = wt + (size_t)lane * 8;
    const int obase = bm * 8 + wm * 4;

    f32x4 acc[4][7];
#pragma unroll
    for (int m = 0; m < 4; ++m)
#pragma unroll
        for (int f = 0; f < 7; ++f) acc[m][f] = (f32x4){0.f, 0.f, 0.f, 0.f};

    // stage via global->LDS DMA: wave wv covers runs wv*6..wv*6+5; run = 1024 B
    // = 16 slots; lane L writes dest run*1024 + L*16 (HW-fixed), so the source
    // supplies slot (run*16 + L/4), unit (L&3) -> k-group g = (L&3)^((L>>2)&3).
    const int s_ww0 = lane >> 2;                       // slot-in-run
    const int s_gg  = (lane & 3) ^ ((lane >> 2) & 3);  // source k-group
    auto stage = [&](int c8, int buf) {
#pragma unroll
        for (int i = 0; i < 6; ++i) {
            const int run = wv * 6 + i;                // 0..23
            const int r   = run >> 2;
            const int ww  = (run & 3) * 16 + s_ww0;
            const unsigned short* src =
                xt + (((size_t)n * 8 + c8) * 58 + h0 + r) * 2048 + ww * 32 + s_gg * 8;
            __builtin_amdgcn_global_load_lds(
                (const __attribute__((address_space(1))) unsigned int*)src,
                (__attribute__((address_space(3))) unsigned int*)
                    (((char*)&xs[buf][0]) + run * 1024),
                16, 0, 0);
        }
    };
    auto a_load = [&](bf16x8* dst, int c8, int t) {
#pragma unroll
        for (int m = 0; m < 4; ++m)
            dst[m] = *(const bf16x8*)(wl + (size_t)((t * 8 + c8) * 16 + obase + m) * 512);
    };

    stage(0, 0);
    __syncthreads();   // drains the DMA (vmcnt 0) before first reads

    for (int c8 = 0; c8 < 8; ++c8) {
        const bool more = c8 < 7;
        const char* xb = (const char*)&xs[c8 & 1][0];

        bf16x8 a0[4], a1[4];
        a_load(a0, c8, 0);

#pragma unroll
        for (int t = 0; t < 9; ++t) {
            bf16x8* ac = (t & 1) ? a1 : a0;
            bf16x8* an = (t & 1) ? a0 : a1;
            if (t < 8) a_load(an, c8, t + 1);
            else if (more) stage(c8 + 1, (c8 + 1) & 1);   // DMA covered by tap-8 MFMAs

            const int kh = t / 3, kw = t % 3;
            const int dt = kh * 4096;            // compile-time under unroll
            __builtin_amdgcn_s_setprio(1);
#pragma unroll
            for (int f = 0; f < 7; ++f) {
                bf16x8 b = *(const bf16x8*)(xb + bboff[f][kw] + dt);
#pragma unroll
                for (int m = 0; m < 4; ++m)
                    acc[m][f] = __builtin_amdgcn_mfma_f32_16x16x32_bf16(ac[m], b, acc[m][f], 0, 0, 0);
            }
            __builtin_amdgcn_s_setprio(0);
        }
        __syncthreads();   // waits stage DMA (issued ~1 tap ago; L2-resident via swizzle)
    }

    // epilogue: D col = lane&15 (spatial), row = 4g+q (out-ch within 16)
#pragma unroll
    for (int m = 0; m < 4; ++m) {
#pragma unroll
        for (int q = 0; q < 4; ++q) {
            int o = bm * 128 + wm * 64 + m * 16 + 4 * g + q;
            float bs = bias[o];
            float* yo = out + ((size_t)n * 256 + o) * HWHW + hb * 224;
#pragma unroll
            for (int f = 0; f < 7; ++f) {
                int j = ng * 112 + f * 16 + lcol;
                yo[j] = acc[m][f][q] + bs;
            }
        }
    }
}

// ---------------- fallback (round-2 kernel) if ws is too small ----------------
__global__ __launch_bounds__(512, 2)
void conv_fallback(const float* __restrict__ x, const unsigned short* __restrict__ wt,
                   const float* __restrict__ bias, float* __restrict__ out) {
    __shared__ short xs[2][348 * 40];
    const int hb = blockIdx.x, n = blockIdx.y, h0 = hb * 4;
    const int tid = threadIdx.x, lane = tid & 63, wv = tid >> 6;
    const int wm = wv & 3, ng = wv >> 2, g = lane >> 4, lcol = lane & 15;
    int bbase[7];
#pragma unroll
    for (int f = 0; f < 7; ++f) {
        int j = ng * 112 + f * 16 + lcol;
        bbase[f] = ((j / 56) * 58 + (j % 56)) * 40 + 8 * g;
    }
    const int cpair = tid >> 5, col0 = tid & 31;
    const float* xn = x + (size_t)n * 256 * HWHW;
    float sv0[6][2], sv1[6][2];
    f32x4 acc[4][7];
#pragma unroll
    for (int m = 0; m < 4; ++m)
#pragma unroll
        for (int f = 0; f < 7; ++f) acc[m][f] = (f32x4){0.f, 0.f, 0.f, 0.f};
    const unsigned short* wl = wt + (size_t)lane * 8;
    auto stage_load = [&](int c8) {
        const float* xc0 = xn + (size_t)(c8 * 32 + 2 * cpair) * HWHW;
        const float* xc1 = xc0 + HWHW;
#pragma unroll
        for (int r = 0; r < 6; ++r) {
            int hh = h0 - 1 + r;
            bool rok = (hh >= 0) & (hh < 56);
#pragma unroll
            for (int ci = 0; ci < 2; ++ci) {
                int col = col0 + 32 * ci, ww = col - 1;
                bool ok = rok & (col < 58) & (ww >= 0) & (ww < 56);
                int off = hh * 56 + ww;
                sv0[r][ci] = ok ? xc0[off] : 0.0f;
                sv1[r][ci] = ok ? xc1[off] : 0.0f;
            }
        }
    };
    auto stage_write = [&](int buf) {
#pragma unroll
        for (int r = 0; r < 6; ++r)
#pragma unroll
            for (int ci = 0; ci < 2; ++ci) {
                int col = col0 + 32 * ci;
                if (col < 58) {
                    unsigned int p = (unsigned int)f2bf(sv0[r][ci]) |
                                     ((unsigned int)f2bf(sv1[r][ci]) << 16);
                    *(unsigned int*)&xs[buf][(r * 58 + col) * 40 + 2 * cpair] = p;
                }
            }
    };
    stage_load(0); stage_write(0);
    __syncthreads();
    for (int c8 = 0; c8 < 8; ++c8) {
        if (c8 < 7) stage_load(c8 + 1);
        const short* xb = &xs[c8 & 1][0];
        bf16x8 a0[4], a1[4];
#pragma unroll
        for (int m = 0; m < 4; ++m)
            a0[m] = *(const bf16x8*)(wl + (size_t)((c8 * 16) + 4 * wm + m) * 512);
#pragma unroll
        for (int t = 0; t < 9; ++t) {
            bf16x8* ac = (t & 1) ? a1 : a0;
            bf16x8* an = (t & 1) ? a0 : a1;
            if (t < 8) {
#pragma unroll
                for (int m = 0; m < 4; ++m)
                    an[m] = *(const bf16x8*)(wl + (size_t)((((t + 1) * 8 + c8) * 16) + 4 * wm + m) * 512);
            }
            const int dt = ((t / 3) * 58 + (t % 3)) * 40;
#pragma unroll
            for (int f = 0; f < 7; ++f) {
                bf16x8 b = *(const bf16x8*)&xb[bbase[f] + dt];
#pragma unroll
                for (int m = 0; m < 4; ++m)
                    acc[m][f] = __builtin_amdgcn_mfma_f32_16x16x32_bf16(ac[m], b, acc[m][f], 0, 0, 0);
            }
        }
        if (c8 < 7) stage_write((c8 + 1) & 1);
        __syncthreads();
    }
#pragma unroll
    for (int m = 0; m < 4; ++m) {
#pragma unroll
        for (int q = 0; q < 4; ++q) {
            int o = 64 * wm + 16 * m + 4 * g + q;
            float bs = bias[o];
            float* yo = out + ((size_t)n * 256 + o) * HWHW + h0 * 56;
#pragma unroll
            for (int f = 0; f < 7; ++f) {
                int j = ng * 112 + f * 16 + lcol;
                yo[j] = acc[m][f][q] + bs;
            }
        }
    }
}

extern "C" void kernel_launch(void* const* d_in, const int* in_sizes, int n_in,
                              void* d_out, int out_size, void* d_ws, size_t ws_size,
                              hipStream_t stream) {
    const float* x    = (const float*)d_in[0];
    const float* w    = (const float*)d_in[1];
    const float* bias = (const float*)d_in[2];
    float* out        = (float*)d_out;
    unsigned short* wt = (unsigned short*)d_ws;                       // 1,179,648 B
    unsigned short* xtp = (unsigned short*)((char*)d_ws + 1179648);   // 60,817,408 B

    wprep<<<2304, 256, 0, stream>>>(w, wt);
    if (ws_size >= (size_t)1179648 + 60817408) {
        xprep<<<dim3(58, 8, 32), 256, 0, stream>>>(x, xtp);
        conv_main<<<896, 256, 0, stream>>>(xtp, wt, bias, out);
    } else {
        conv_fallback<<<dim3(14, 32), 512, 0, stream>>>(x, wt, bias, out);
    }
}